// Round 4
// baseline (149.519 us; speedup 1.0000x reference)
//
#include <hip/hip_runtime.h>

// Problem dims (fixed by setup_inputs): B=4, S=1024, T=256, H=512, A=256
#define B_ 4
#define S_ 1024
#define T_ 256
#define H_ 512
#define A_ 256
#define TT 4   // t-rows per score block

typedef __attribute__((ext_vector_type(8))) short short8;   // 8 bf16 = 4 VGPR
typedef __attribute__((ext_vector_type(4))) float f32x4;    // MFMA acc

__device__ __forceinline__ float ex2(float x)   { return __builtin_amdgcn_exp2f(x); }
__device__ __forceinline__ float rcpf_(float x) { return __builtin_amdgcn_rcpf(x); }

#define K2F 2.8853900817779268f     // 2*log2(e): exp(2x) = exp2(K2F*x)
#define LOG2EF 1.4426950408889634f

// fp32 -> bf16 split: x ~= hi + lo (both bf16, RNE). Dropped lo*lo term in
// products is ~2^-18 relative -> negligible vs 1.9e-4 threshold.
__device__ __forceinline__ void split_bf16(float x, unsigned short& h, unsigned short& l)
{
    unsigned u = __float_as_uint(x);
    unsigned r = (u + 0x7FFFu + ((u >> 16) & 1u)) >> 16;
    h = (unsigned short)r;
    float hf = __uint_as_float(r << 16);
    float lo = x - hf;                       // exact in fp32
    unsigned u2 = __float_as_uint(lo);
    l = (unsigned short)((u2 + 0x7FFFu + ((u2 >> 16) & 1u)) >> 16);
}

// ---------------------------------------------------------------------------
// Kernel 0: transpose + bf16-split W matrices.  W[k][a] -> WT_hi/lo[a][k].
// ---------------------------------------------------------------------------
__global__ __launch_bounds__(256)
void prep_w(const float* __restrict__ Wh, const float* __restrict__ Wsm,
            unsigned short* __restrict__ WhTh, unsigned short* __restrict__ WhTl,
            unsigned short* __restrict__ WsTh, unsigned short* __restrict__ WsTl)
{
    __shared__ float lds[32][36];
    const int tid = threadIdx.x, bid = blockIdx.x;
    const int mat = bid >> 7, rem = bid & 127;
    const int k0 = (rem & 15) * 32, a0 = (rem >> 4) * 32;
    const float* W = mat ? Wsm : Wh;
    unsigned short* Oh = mat ? WsTh : WhTh;
    unsigned short* Ol = mat ? WsTl : WhTl;

    {
        int kl = tid >> 3, a4 = (tid & 7) * 4;
        float4 v = *(const float4*)&W[(size_t)(k0 + kl) * A_ + a0 + a4];
        lds[kl][a4] = v.x; lds[kl][a4 + 1] = v.y; lds[kl][a4 + 2] = v.z; lds[kl][a4 + 3] = v.w;
    }
    __syncthreads();
    {
        int al = tid >> 3, k4 = (tid & 7) * 4;
        unsigned short h[4], l[4];
        #pragma unroll
        for (int i = 0; i < 4; ++i) split_bf16(lds[k4 + i][al], h[i], l[i]);
        size_t o = (size_t)(a0 + al) * H_ + k0 + k4;
        *(ushort4*)&Oh[o] = make_ushort4(h[0], h[1], h[2], h[3]);
        *(ushort4*)&Ol[o] = make_ushort4(l[0], l[1], l[2], l[3]);
    }
}

// ---------------------------------------------------------------------------
// Kernel 1: split-bf16 MFMA GEMM + exp epilogue (unchanged from round 3).
//   blocks [0,256):   E[b][a][s] = exp(2*(enc@Wh + bh))  (transposed store)
//   blocks [256,320): D[m][a]    = exp(2*(dec@Ws + bs))  (row-major store)
// ---------------------------------------------------------------------------
__global__ __launch_bounds__(256)
void gemm_mfma(const float* __restrict__ enc, const float* __restrict__ dec,
               const unsigned short* __restrict__ WhTh, const unsigned short* __restrict__ WhTl,
               const unsigned short* __restrict__ WsTh, const unsigned short* __restrict__ WsTl,
               const float* __restrict__ bh, const float* __restrict__ bs,
               float* __restrict__ Ebuf, float* __restrict__ Dbuf)
{
    __shared__ short smem[8192];          // 16 KB: Ahi|Alo|Bhi|Blo, 4KB each
    short* Ah = smem;
    short* Al = smem + 2048;
    short* Bh = smem + 4096;
    short* Bl = smem + 6144;

    const int tid = threadIdx.x, bid = blockIdx.x;
    const bool isE = bid < 256;
    int mb, nb;
    const float* Ag; const unsigned short* WTh; const unsigned short* WTl; const float* bias;
    if (isE) { mb = (bid & 63) * 64; nb = (bid >> 6) * 64; Ag = enc; WTh = WhTh; WTl = WhTl; bias = bh; }
    else { int b2 = bid - 256; mb = (b2 & 15) * 64; nb = (b2 >> 4) * 64; Ag = dec; WTh = WsTh; WTl = WsTl; bias = bs; }

    const int m_l = tid >> 2, q = tid & 3;
    const size_t arow = (size_t)(mb + m_l) * H_ + 8 * q;   // A: fp32 [m][k]
    const size_t brow = (size_t)(nb + m_l) * H_ + 8 * q;   // WT: bf16 [a][k]
    const int woff = ((m_l >> 4) * 64 + (m_l & 15) + 16 * q) * 8;  // frag-major slot

    const int wave = tid >> 6, lane = tid & 63;
    const int wm = wave >> 1, wn = wave & 1;
    const int roffA = (2 * wm) * 512 + lane * 8;
    const int roffB = (2 * wn) * 512 + lane * 8;

    const int cl = lane & 15, rg = lane >> 4;
    const float bias0 = bias[nb + wn * 32 + cl];
    const float bias1 = bias[nb + wn * 32 + 16 + cl];

    f32x4 acc[2][2] = {};

    float4 aA = *(const float4*)&Ag[arow];
    float4 aB = *(const float4*)&Ag[arow + 4];
    short8 bHv = *(const short8*)&WTh[brow];
    short8 bLv = *(const short8*)&WTl[brow];

    for (int it = 0; it < 16; ++it) {
        __syncthreads();
        {
            float xs[8] = {aA.x, aA.y, aA.z, aA.w, aB.x, aB.y, aB.z, aB.w};
            short8 hv, lv;
            #pragma unroll
            for (int j = 0; j < 8; ++j) {
                unsigned short h, l; split_bf16(xs[j], h, l);
                hv[j] = (short)h; lv[j] = (short)l;
            }
            *(short8*)&Ah[woff] = hv;
            *(short8*)&Al[woff] = lv;
            *(short8*)&Bh[woff] = bHv;
            *(short8*)&Bl[woff] = bLv;
        }
        if (it < 15) {
            int kn = (it + 1) * 32;
            aA  = *(const float4*)&Ag[arow + kn];
            aB  = *(const float4*)&Ag[arow + kn + 4];
            bHv = *(const short8*)&WTh[brow + kn];
            bLv = *(const short8*)&WTl[brow + kn];
        }
        __syncthreads();
        short8 fAh0 = *(short8*)&Ah[roffA], fAh1 = *(short8*)&Ah[roffA + 512];
        short8 fAl0 = *(short8*)&Al[roffA], fAl1 = *(short8*)&Al[roffA + 512];
        short8 fBh0 = *(short8*)&Bh[roffB], fBh1 = *(short8*)&Bh[roffB + 512];
        short8 fBl0 = *(short8*)&Bl[roffB], fBl1 = *(short8*)&Bl[roffB + 512];
        acc[0][0] = __builtin_amdgcn_mfma_f32_16x16x32_bf16(fAh0, fBh0, acc[0][0], 0, 0, 0);
        acc[0][0] = __builtin_amdgcn_mfma_f32_16x16x32_bf16(fAh0, fBl0, acc[0][0], 0, 0, 0);
        acc[0][0] = __builtin_amdgcn_mfma_f32_16x16x32_bf16(fAl0, fBh0, acc[0][0], 0, 0, 0);
        acc[0][1] = __builtin_amdgcn_mfma_f32_16x16x32_bf16(fAh0, fBh1, acc[0][1], 0, 0, 0);
        acc[0][1] = __builtin_amdgcn_mfma_f32_16x16x32_bf16(fAh0, fBl1, acc[0][1], 0, 0, 0);
        acc[0][1] = __builtin_amdgcn_mfma_f32_16x16x32_bf16(fAl0, fBh1, acc[0][1], 0, 0, 0);
        acc[1][0] = __builtin_amdgcn_mfma_f32_16x16x32_bf16(fAh1, fBh0, acc[1][0], 0, 0, 0);
        acc[1][0] = __builtin_amdgcn_mfma_f32_16x16x32_bf16(fAh1, fBl0, acc[1][0], 0, 0, 0);
        acc[1][0] = __builtin_amdgcn_mfma_f32_16x16x32_bf16(fAl1, fBh0, acc[1][0], 0, 0, 0);
        acc[1][1] = __builtin_amdgcn_mfma_f32_16x16x32_bf16(fAh1, fBh1, acc[1][1], 0, 0, 0);
        acc[1][1] = __builtin_amdgcn_mfma_f32_16x16x32_bf16(fAh1, fBl1, acc[1][1], 0, 0, 0);
        acc[1][1] = __builtin_amdgcn_mfma_f32_16x16x32_bf16(fAl1, fBh1, acc[1][1], 0, 0, 0);
    }

    #pragma unroll
    for (int mf = 0; mf < 2; ++mf) {
        const int mg = mb + wm * 32 + mf * 16 + rg * 4;
        #pragma unroll
        for (int nf = 0; nf < 2; ++nf) {
            const int a = nb + wn * 32 + nf * 16 + cl;
            const float bb = nf ? bias1 : bias0;
            f32x4 ac = acc[mf][nf];
            float4 st;
            st.x = ex2((ac[0] + bb) * K2F);
            st.y = ex2((ac[1] + bb) * K2F);
            st.z = ex2((ac[2] + bb) * K2F);
            st.w = ex2((ac[3] + bb) * K2F);
            if (isE) {
                const int b = mg >> 10, s = mg & 1023;
                *(float4*)&Ebuf[(((size_t)b * A_ + a) << 10) + s] = st;
            } else {
                Dbuf[(size_t)(mg + 0) * A_ + a] = st.x;
                Dbuf[(size_t)(mg + 1) * A_ + a] = st.y;
                Dbuf[(size_t)(mg + 2) * A_ + a] = st.z;
                Dbuf[(size_t)(mg + 3) * A_ + a] = st.w;
            }
        }
    }
}

// ---------------------------------------------------------------------------
// Kernel 2: fused score + softmax.
// block = (b, 4 t-rows); 1024 threads, each owns ONE s column.
// score'[t][s] = -2 * sum_a Wv[a] / (E[b,a,s]*D[b,t,a] + 1)
// D/Wv are wave-uniform values but are forced onto the VECTOR memory path
// (opaque-zero VGPR in the address) -- round-3 profile showed the compiler's
// scalar-cache s_loads serialize across the CU's 16 waves (VGPR=32/SGPR=80,
// implied VALUBusy ~25%). Same-address vector loads broadcast from L1.
// D fragments are double-buffered one half-chunk ahead, like E.
// ---------------------------------------------------------------------------
__device__ __forceinline__ void pair_acc(float e1, float e2, float d1, float d2,
                                         float w1, float w2, float& acc)
{
    float q1  = fmaf(e1, d1, 1.0f);
    float q2  = fmaf(e2, d2, 1.0f);
    float num = fmaf(w1, q2, w2 * q1);
    acc = fmaf(num, rcpf_(q1 * q2), acc);
}

__global__ __launch_bounds__(1024, 4)
void score_softmax(const float* __restrict__ E, const float* __restrict__ D,
                   const float* __restrict__ Wv, float* __restrict__ out)
{
    const int tid = threadIdx.x;          // = s column
    const int b  = blockIdx.x >> 6;
    const int t0 = (blockIdx.x & 63) * TT;

    __shared__ float redm[TT][16];
    __shared__ float reds[TT][16];

    // opaque zero in a VGPR: compiler can't prove uniformity -> VMEM loads
    int vz = 0;
    asm volatile("" : "+v"(vz));

    const float* Eb = E + (size_t)b * A_ * S_ + tid;
    const float* Dg = D + ((size_t)b * T_ + t0) * A_ + vz;
    const float* Wz = Wv + vz;

    float acc[TT] = {};

    float  evA[8], evB[8];
    float4 dA[TT][2], dB[TT][2];

    #pragma unroll
    for (int u = 0; u < 8; ++u) evA[u] = Eb[(size_t)u * S_];
    #pragma unroll
    for (int t = 0; t < TT; ++t) {
        dA[t][0] = *(const float4*)&Dg[t * A_ + 0];
        dA[t][1] = *(const float4*)&Dg[t * A_ + 4];
    }

#define HALF(EV, DW, A0)                                                        \
    {                                                                           \
        float4 w0 = *(const float4*)&Wz[(A0)];                                  \
        float4 w1 = *(const float4*)&Wz[(A0) + 4];                              \
        _Pragma("unroll")                                                       \
        for (int t = 0; t < TT; ++t) {                                          \
            pair_acc(EV[0], EV[1], DW[t][0].x, DW[t][0].y, w0.x, w0.y, acc[t]); \
            pair_acc(EV[2], EV[3], DW[t][0].z, DW[t][0].w, w0.z, w0.w, acc[t]); \
            pair_acc(EV[4], EV[5], DW[t][1].x, DW[t][1].y, w1.x, w1.y, acc[t]); \
            pair_acc(EV[6], EV[7], DW[t][1].z, DW[t][1].w, w1.z, w1.w, acc[t]); \
        }                                                                       \
    }

    for (int a0 = 0; a0 < A_; a0 += 16) {
        #pragma unroll
        for (int u = 0; u < 8; ++u) evB[u] = Eb[(size_t)(a0 + 8 + u) * S_];
        #pragma unroll
        for (int t = 0; t < TT; ++t) {
            dB[t][0] = *(const float4*)&Dg[t * A_ + a0 + 8];
            dB[t][1] = *(const float4*)&Dg[t * A_ + a0 + 12];
        }
        HALF(evA, dA, a0);
        if (a0 + 16 < A_) {
            #pragma unroll
            for (int u = 0; u < 8; ++u) evA[u] = Eb[(size_t)(a0 + 16 + u) * S_];
            #pragma unroll
            for (int t = 0; t < TT; ++t) {
                dA[t][0] = *(const float4*)&Dg[t * A_ + a0 + 16];
                dA[t][1] = *(const float4*)&Dg[t * A_ + a0 + 20];
            }
        }
        HALF(evB, dB, a0 + 8);
    }
#undef HALF

    // ---- softmax over s (per t row), 16-wave block reduction ----
    const int lane = tid & 63, wid = tid >> 6;
    float sc[TT];
    #pragma unroll
    for (int t = 0; t < TT; ++t) sc[t] = -2.0f * acc[t];

    #pragma unroll
    for (int t = 0; t < TT; ++t) {
        float mx = sc[t];
        #pragma unroll
        for (int off = 32; off > 0; off >>= 1) mx = fmaxf(mx, __shfl_xor(mx, off, 64));
        if (lane == 0) redm[t][wid] = mx;
    }
    __syncthreads();

    float mrow[TT];
    #pragma unroll
    for (int t = 0; t < TT; ++t) {
        float m = redm[t][0];
        #pragma unroll
        for (int i = 1; i < 16; ++i) m = fmaxf(m, redm[t][i]);
        mrow[t] = m;
    }

    #pragma unroll
    for (int t = 0; t < TT; ++t) {
        sc[t] = ex2((sc[t] - mrow[t]) * LOG2EF);
        float s = sc[t];
        #pragma unroll
        for (int off = 32; off > 0; off >>= 1) s += __shfl_xor(s, off, 64);
        if (lane == 0) reds[t][wid] = s;
    }
    __syncthreads();

    #pragma unroll
    for (int t = 0; t < TT; ++t) {
        float ssum = reds[t][0];
        #pragma unroll
        for (int i = 1; i < 16; ++i) ssum += reds[t][i];
        float inv = 1.0f / ssum;
        out[((size_t)b * T_ + (t0 + t)) * S_ + tid] = sc[t] * inv;
    }
}

// ---------------------------------------------------------------------------
extern "C" void kernel_launch(void* const* d_in, const int* in_sizes, int n_in,
                              void* d_out, int out_size, void* d_ws, size_t ws_size,
                              hipStream_t stream)
{
    const float* enc = (const float*)d_in[0];
    const float* dec = (const float*)d_in[1];
    const float* Wh  = (const float*)d_in[2];
    const float* bh  = (const float*)d_in[3];
    const float* Wsm = (const float*)d_in[4];
    const float* bs  = (const float*)d_in[5];
    const float* Wv  = (const float*)d_in[6];
    // d_in[7] (bv) intentionally unused: softmax is shift-invariant.

    float* Ebuf = (float*)d_ws;                              // 1M floats (4 MB)
    float* Dbuf = Ebuf + (size_t)B_ * A_ * S_;               // 256K floats (1 MB)
    unsigned short* wt = (unsigned short*)(Dbuf + (size_t)B_ * T_ * A_);
    unsigned short* WhTh = wt;                               // 256x512 bf16 each
    unsigned short* WhTl = wt + 131072;
    unsigned short* WsTh = wt + 262144;
    unsigned short* WsTl = wt + 393216;

    prep_w<<<256, 256, 0, stream>>>(Wh, Wsm, WhTh, WhTl, WsTh, WsTl);
    gemm_mfma<<<320, 256, 0, stream>>>(enc, dec, WhTh, WhTl, WsTh, WsTl,
                                       bh, bs, Ebuf, Dbuf);
    score_softmax<<<B_ * (T_ / TT), 1024, 0, stream>>>(Ebuf, Dbuf, Wv, (float*)d_out);
}

// Round 5
// 66.766 us; speedup vs baseline: 2.2394x; 2.2394x over previous
//
#include <hip/hip_runtime.h>

// Problem dims (fixed by setup_inputs): B=4, S=1024, T=256, H=512, A=256
#define B_ 4
#define S_ 1024
#define T_ 256
#define H_ 512
#define A_ 256

typedef __attribute__((ext_vector_type(8))) short short8;   // 8 bf16 = 4 VGPR
typedef __attribute__((ext_vector_type(4))) float f32x4;    // MFMA acc

__device__ __forceinline__ float ex2(float x)   { return __builtin_amdgcn_exp2f(x); }
__device__ __forceinline__ float rcpf_(float x) { return __builtin_amdgcn_rcpf(x); }

#define K2F 2.8853900817779268f     // 2*log2(e): exp(2x) = exp2(K2F*x)
#define LOG2EF 1.4426950408889634f

// fp32 -> bf16 split: x ~= hi + lo (both bf16, RNE). Dropped lo*lo term in
// products is ~2^-18 relative -> negligible vs 1.9e-4 threshold.
__device__ __forceinline__ void split_bf16(float x, unsigned short& h, unsigned short& l)
{
    unsigned u = __float_as_uint(x);
    unsigned r = (u + 0x7FFFu + ((u >> 16) & 1u)) >> 16;
    h = (unsigned short)r;
    float hf = __uint_as_float(r << 16);
    float lo = x - hf;                       // exact in fp32
    unsigned u2 = __float_as_uint(lo);
    l = (unsigned short)((u2 + 0x7FFFu + ((u2 >> 16) & 1u)) >> 16);
}

// ---------------------------------------------------------------------------
// Kernel 0: transpose + bf16-split W matrices.  W[k][a] -> WT_hi/lo[a][k].
// ---------------------------------------------------------------------------
__global__ __launch_bounds__(256)
void prep_w(const float* __restrict__ Wh, const float* __restrict__ Wsm,
            unsigned short* __restrict__ WhTh, unsigned short* __restrict__ WhTl,
            unsigned short* __restrict__ WsTh, unsigned short* __restrict__ WsTl)
{
    __shared__ float lds[32][36];
    const int tid = threadIdx.x, bid = blockIdx.x;
    const int mat = bid >> 7, rem = bid & 127;
    const int k0 = (rem & 15) * 32, a0 = (rem >> 4) * 32;
    const float* W = mat ? Wsm : Wh;
    unsigned short* Oh = mat ? WsTh : WhTh;
    unsigned short* Ol = mat ? WsTl : WhTl;

    {
        int kl = tid >> 3, a4 = (tid & 7) * 4;
        float4 v = *(const float4*)&W[(size_t)(k0 + kl) * A_ + a0 + a4];
        lds[kl][a4] = v.x; lds[kl][a4 + 1] = v.y; lds[kl][a4 + 2] = v.z; lds[kl][a4 + 3] = v.w;
    }
    __syncthreads();
    {
        int al = tid >> 3, k4 = (tid & 7) * 4;
        unsigned short h[4], l[4];
        #pragma unroll
        for (int i = 0; i < 4; ++i) split_bf16(lds[k4 + i][al], h[i], l[i]);
        size_t o = (size_t)(a0 + al) * H_ + k0 + k4;
        *(ushort4*)&Oh[o] = make_ushort4(h[0], h[1], h[2], h[3]);
        *(ushort4*)&Ol[o] = make_ushort4(l[0], l[1], l[2], l[3]);
    }
}

// ---------------------------------------------------------------------------
// Kernel 1: split-bf16 MFMA GEMM + exp epilogue (unchanged, known-good).
//   blocks [0,256):   E[b][a][s] = exp(2*(enc@Wh + bh))  (transposed store)
//   blocks [256,320): D[m][a]    = exp(2*(dec@Ws + bs))  (row-major store)
// ---------------------------------------------------------------------------
__global__ __launch_bounds__(256)
void gemm_mfma(const float* __restrict__ enc, const float* __restrict__ dec,
               const unsigned short* __restrict__ WhTh, const unsigned short* __restrict__ WhTl,
               const unsigned short* __restrict__ WsTh, const unsigned short* __restrict__ WsTl,
               const float* __restrict__ bh, const float* __restrict__ bs,
               float* __restrict__ Ebuf, float* __restrict__ Dbuf)
{
    __shared__ short smem[8192];          // 16 KB: Ahi|Alo|Bhi|Blo, 4KB each
    short* Ah = smem;
    short* Al = smem + 2048;
    short* Bh = smem + 4096;
    short* Bl = smem + 6144;

    const int tid = threadIdx.x, bid = blockIdx.x;
    const bool isE = bid < 256;
    int mb, nb;
    const float* Ag; const unsigned short* WTh; const unsigned short* WTl; const float* bias;
    if (isE) { mb = (bid & 63) * 64; nb = (bid >> 6) * 64; Ag = enc; WTh = WhTh; WTl = WhTl; bias = bh; }
    else { int b2 = bid - 256; mb = (b2 & 15) * 64; nb = (b2 >> 4) * 64; Ag = dec; WTh = WsTh; WTl = WsTl; bias = bs; }

    const int m_l = tid >> 2, q = tid & 3;
    const size_t arow = (size_t)(mb + m_l) * H_ + 8 * q;   // A: fp32 [m][k]
    const size_t brow = (size_t)(nb + m_l) * H_ + 8 * q;   // WT: bf16 [a][k]
    const int woff = ((m_l >> 4) * 64 + (m_l & 15) + 16 * q) * 8;  // frag-major slot

    const int wave = tid >> 6, lane = tid & 63;
    const int wm = wave >> 1, wn = wave & 1;
    const int roffA = (2 * wm) * 512 + lane * 8;
    const int roffB = (2 * wn) * 512 + lane * 8;

    const int cl = lane & 15, rg = lane >> 4;
    const float bias0 = bias[nb + wn * 32 + cl];
    const float bias1 = bias[nb + wn * 32 + 16 + cl];

    f32x4 acc[2][2] = {};

    float4 aA = *(const float4*)&Ag[arow];
    float4 aB = *(const float4*)&Ag[arow + 4];
    short8 bHv = *(const short8*)&WTh[brow];
    short8 bLv = *(const short8*)&WTl[brow];

    for (int it = 0; it < 16; ++it) {
        __syncthreads();
        {
            float xs[8] = {aA.x, aA.y, aA.z, aA.w, aB.x, aB.y, aB.z, aB.w};
            short8 hv, lv;
            #pragma unroll
            for (int j = 0; j < 8; ++j) {
                unsigned short h, l; split_bf16(xs[j], h, l);
                hv[j] = (short)h; lv[j] = (short)l;
            }
            *(short8*)&Ah[woff] = hv;
            *(short8*)&Al[woff] = lv;
            *(short8*)&Bh[woff] = bHv;
            *(short8*)&Bl[woff] = bLv;
        }
        if (it < 15) {
            int kn = (it + 1) * 32;
            aA  = *(const float4*)&Ag[arow + kn];
            aB  = *(const float4*)&Ag[arow + kn + 4];
            bHv = *(const short8*)&WTh[brow + kn];
            bLv = *(const short8*)&WTl[brow + kn];
        }
        __syncthreads();
        short8 fAh0 = *(short8*)&Ah[roffA], fAh1 = *(short8*)&Ah[roffA + 512];
        short8 fAl0 = *(short8*)&Al[roffA], fAl1 = *(short8*)&Al[roffA + 512];
        short8 fBh0 = *(short8*)&Bh[roffB], fBh1 = *(short8*)&Bh[roffB + 512];
        short8 fBl0 = *(short8*)&Bl[roffB], fBl1 = *(short8*)&Bl[roffB + 512];
        acc[0][0] = __builtin_amdgcn_mfma_f32_16x16x32_bf16(fAh0, fBh0, acc[0][0], 0, 0, 0);
        acc[0][0] = __builtin_amdgcn_mfma_f32_16x16x32_bf16(fAh0, fBl0, acc[0][0], 0, 0, 0);
        acc[0][0] = __builtin_amdgcn_mfma_f32_16x16x32_bf16(fAl0, fBh0, acc[0][0], 0, 0, 0);
        acc[0][1] = __builtin_amdgcn_mfma_f32_16x16x32_bf16(fAh0, fBh1, acc[0][1], 0, 0, 0);
        acc[0][1] = __builtin_amdgcn_mfma_f32_16x16x32_bf16(fAh0, fBl1, acc[0][1], 0, 0, 0);
        acc[0][1] = __builtin_amdgcn_mfma_f32_16x16x32_bf16(fAl0, fBh1, acc[0][1], 0, 0, 0);
        acc[1][0] = __builtin_amdgcn_mfma_f32_16x16x32_bf16(fAh1, fBh0, acc[1][0], 0, 0, 0);
        acc[1][0] = __builtin_amdgcn_mfma_f32_16x16x32_bf16(fAh1, fBl0, acc[1][0], 0, 0, 0);
        acc[1][0] = __builtin_amdgcn_mfma_f32_16x16x32_bf16(fAl1, fBh0, acc[1][0], 0, 0, 0);
        acc[1][1] = __builtin_amdgcn_mfma_f32_16x16x32_bf16(fAh1, fBh1, acc[1][1], 0, 0, 0);
        acc[1][1] = __builtin_amdgcn_mfma_f32_16x16x32_bf16(fAh1, fBl1, acc[1][1], 0, 0, 0);
        acc[1][1] = __builtin_amdgcn_mfma_f32_16x16x32_bf16(fAl1, fBh1, acc[1][1], 0, 0, 0);
    }

    #pragma unroll
    for (int mf = 0; mf < 2; ++mf) {
        const int mg = mb + wm * 32 + mf * 16 + rg * 4;
        #pragma unroll
        for (int nf = 0; nf < 2; ++nf) {
            const int a = nb + wn * 32 + nf * 16 + cl;
            const float bb = nf ? bias1 : bias0;
            f32x4 ac = acc[mf][nf];
            float4 st;
            st.x = ex2((ac[0] + bb) * K2F);
            st.y = ex2((ac[1] + bb) * K2F);
            st.z = ex2((ac[2] + bb) * K2F);
            st.w = ex2((ac[3] + bb) * K2F);
            if (isE) {
                const int b = mg >> 10, s = mg & 1023;
                *(float4*)&Ebuf[(((size_t)b * A_ + a) << 10) + s] = st;
            } else {
                Dbuf[(size_t)(mg + 0) * A_ + a] = st.x;
                Dbuf[(size_t)(mg + 1) * A_ + a] = st.y;
                Dbuf[(size_t)(mg + 2) * A_ + a] = st.z;
                Dbuf[(size_t)(mg + 3) * A_ + a] = st.w;
            }
        }
    }
}

// ---------------------------------------------------------------------------
// Kernel 2: fused score + softmax, v2.
// block = (b, 2 t-rows); 512 threads, each owns TWO adjacent s columns.
// score'[t][s] = -2 * sum_a Wv[a] / (E[b,a,s]*D[b,t,a] + 1)
// D/Wv staged ONCE in LDS (3 KB); inner loop reads them via uniform-address
// ds_read_b128 (hardware broadcast, conflict-free). Each D/Wv register load
// feeds BOTH s columns -> operand traffic per wave is 768 floats (vs 1280
// scalar-loads in the round-3 version whose scalar pipe serialized).
// E loads are coalesced float2 (adjacent columns), double-buffered.
// No launch_bounds cap: natural VGPR (~100) keeps 2 blocks/CU = 4 waves/SIMD.
// ---------------------------------------------------------------------------
__device__ __forceinline__ void pair_acc(float e1, float e2, float d1, float d2,
                                         float w1, float w2, float& acc)
{
    float q1  = fmaf(e1, d1, 1.0f);
    float q2  = fmaf(e2, d2, 1.0f);
    float num = fmaf(w1, q2, w2 * q1);
    acc = fmaf(num, rcpf_(q1 * q2), acc);
}

#define LD8(dst, srcp)                                                     \
    { float4 x_ = *(const float4*)(srcp); float4 y_ = *(const float4*)((srcp) + 4); \
      dst[0] = x_.x; dst[1] = x_.y; dst[2] = x_.z; dst[3] = x_.w;          \
      dst[4] = y_.x; dst[5] = y_.y; dst[6] = y_.z; dst[7] = y_.w; }

__global__ __launch_bounds__(512)
void score_softmax(const float* __restrict__ E, const float* __restrict__ D,
                   const float* __restrict__ Wv, float* __restrict__ out)
{
    const int tid = threadIdx.x;
    const int b  = blockIdx.x >> 7;            // 128 blocks per batch
    const int t0 = (blockIdx.x & 127) * 2;

    __shared__ float Dsh[2][A_];
    __shared__ float Wsh[A_];
    __shared__ float redm[2][8];
    __shared__ float reds[2][8];

    if (tid < 128) {
        int r = tid >> 6, c4 = (tid & 63) << 2;
        *(float4*)&Dsh[r][c4] = *(const float4*)&D[((size_t)b * T_ + t0 + r) * A_ + c4];
    } else if (tid < 192) {
        int c4 = (tid - 128) << 2;
        *(float4*)&Wsh[c4] = *(const float4*)&Wv[c4];
    }
    __syncthreads();

    const int s0 = tid << 1;                   // two adjacent s columns
    const float* Eb = E + (size_t)b * A_ * S_ + s0;

    float acc[2][2] = {};                      // [t][col]
    float2 evA[8], evB[8];
    float dA[2][8], dB[2][8], wA[8], wB[8];

    #pragma unroll
    for (int u = 0; u < 8; ++u) evA[u] = *(const float2*)&Eb[(size_t)u * S_];
    #pragma unroll
    for (int t = 0; t < 2; ++t) LD8(dA[t], &Dsh[t][0]);
    LD8(wA, &Wsh[0]);

#define HALF(EV, DD, WW)                                                        \
    _Pragma("unroll")                                                           \
    for (int t = 0; t < 2; ++t) {                                               \
        _Pragma("unroll")                                                       \
        for (int p = 0; p < 4; ++p) {                                           \
            float d1 = DD[t][2 * p], d2 = DD[t][2 * p + 1];                     \
            float w1 = WW[2 * p],    w2 = WW[2 * p + 1];                        \
            pair_acc(EV[2 * p].x, EV[2 * p + 1].x, d1, d2, w1, w2, acc[t][0]);  \
            pair_acc(EV[2 * p].y, EV[2 * p + 1].y, d1, d2, w1, w2, acc[t][1]);  \
        }                                                                       \
    }

    for (int a0 = 0; a0 < A_; a0 += 16) {
        #pragma unroll
        for (int u = 0; u < 8; ++u) evB[u] = *(const float2*)&Eb[(size_t)(a0 + 8 + u) * S_];
        #pragma unroll
        for (int t = 0; t < 2; ++t) LD8(dB[t], &Dsh[t][a0 + 8]);
        LD8(wB, &Wsh[a0 + 8]);
        HALF(evA, dA, wA);
        if (a0 + 16 < A_) {
            #pragma unroll
            for (int u = 0; u < 8; ++u) evA[u] = *(const float2*)&Eb[(size_t)(a0 + 16 + u) * S_];
            #pragma unroll
            for (int t = 0; t < 2; ++t) LD8(dA[t], &Dsh[t][a0 + 16]);
            LD8(wA, &Wsh[a0 + 16]);
        }
        HALF(evB, dB, wB);
    }
#undef HALF

    // ---- softmax over s (per t row): wave shuffle + 8-wave LDS reduce ----
    const int lane = tid & 63, wid = tid >> 6;
    float sc[2][2];
    #pragma unroll
    for (int t = 0; t < 2; ++t) {
        sc[t][0] = -2.0f * acc[t][0];
        sc[t][1] = -2.0f * acc[t][1];
    }

    #pragma unroll
    for (int t = 0; t < 2; ++t) {
        float mx = fmaxf(sc[t][0], sc[t][1]);
        #pragma unroll
        for (int off = 32; off > 0; off >>= 1) mx = fmaxf(mx, __shfl_xor(mx, off, 64));
        if (lane == 0) redm[t][wid] = mx;
    }
    __syncthreads();

    float mrow[2];
    #pragma unroll
    for (int t = 0; t < 2; ++t) {
        float m = redm[t][0];
        #pragma unroll
        for (int i = 1; i < 8; ++i) m = fmaxf(m, redm[t][i]);
        mrow[t] = m;
    }

    #pragma unroll
    for (int t = 0; t < 2; ++t) {
        sc[t][0] = ex2((sc[t][0] - mrow[t]) * LOG2EF);
        sc[t][1] = ex2((sc[t][1] - mrow[t]) * LOG2EF);
        float s = sc[t][0] + sc[t][1];
        #pragma unroll
        for (int off = 32; off > 0; off >>= 1) s += __shfl_xor(s, off, 64);
        if (lane == 0) reds[t][wid] = s;
    }
    __syncthreads();

    #pragma unroll
    for (int t = 0; t < 2; ++t) {
        float ssum = reds[t][0];
        #pragma unroll
        for (int i = 1; i < 8; ++i) ssum += reds[t][i];
        float inv = 1.0f / ssum;
        float2 o = make_float2(sc[t][0] * inv, sc[t][1] * inv);
        *(float2*)&out[((size_t)b * T_ + (t0 + t)) * S_ + s0] = o;
    }
}

// ---------------------------------------------------------------------------
extern "C" void kernel_launch(void* const* d_in, const int* in_sizes, int n_in,
                              void* d_out, int out_size, void* d_ws, size_t ws_size,
                              hipStream_t stream)
{
    const float* enc = (const float*)d_in[0];
    const float* dec = (const float*)d_in[1];
    const float* Wh  = (const float*)d_in[2];
    const float* bh  = (const float*)d_in[3];
    const float* Wsm = (const float*)d_in[4];
    const float* bs  = (const float*)d_in[5];
    const float* Wv  = (const float*)d_in[6];
    // d_in[7] (bv) intentionally unused: softmax is shift-invariant.

    float* Ebuf = (float*)d_ws;                              // 1M floats (4 MB)
    float* Dbuf = Ebuf + (size_t)B_ * A_ * S_;               // 256K floats (1 MB)
    unsigned short* wt = (unsigned short*)(Dbuf + (size_t)B_ * T_ * A_);
    unsigned short* WhTh = wt;                               // 256x512 bf16 each
    unsigned short* WhTl = wt + 131072;
    unsigned short* WsTh = wt + 262144;
    unsigned short* WsTl = wt + 393216;

    prep_w<<<256, 256, 0, stream>>>(Wh, Wsm, WhTh, WhTl, WsTh, WsTl);
    gemm_mfma<<<320, 256, 0, stream>>>(enc, dec, WhTh, WhTl, WsTh, WsTl,
                                       bh, bs, Ebuf, Dbuf);
    score_softmax<<<B_ * (T_ / 2), 512, 0, stream>>>(Ebuf, Dbuf, Wv, (float*)d_out);
}

// Round 6
// 65.570 us; speedup vs baseline: 2.2803x; 1.0183x over previous
//
#include <hip/hip_runtime.h>

// Problem dims (fixed by setup_inputs): B=4, S=1024, T=256, H=512, A=256
#define B_ 4
#define S_ 1024
#define T_ 256
#define H_ 512
#define A_ 256

typedef __attribute__((ext_vector_type(8))) short short8;   // 8 bf16 = 4 VGPR
typedef __attribute__((ext_vector_type(4))) float f32x4;    // MFMA acc
typedef __attribute__((ext_vector_type(2))) float f32x2;    // v_pk_*_f32 pair

__device__ __forceinline__ float ex2(float x)   { return __builtin_amdgcn_exp2f(x); }
__device__ __forceinline__ float rcpf_(float x) { return __builtin_amdgcn_rcpf(x); }
__device__ __forceinline__ f32x2 splat2(float v) { f32x2 r; r.x = v; r.y = v; return r; }

#define K2F 2.8853900817779268f     // 2*log2(e): exp(2x) = exp2(K2F*x)

// fp32 -> bf16 split: x ~= hi + lo (both bf16, RNE).
__device__ __forceinline__ void split_bf16(float x, unsigned short& h, unsigned short& l)
{
    unsigned u = __float_as_uint(x);
    unsigned r = (u + 0x7FFFu + ((u >> 16) & 1u)) >> 16;
    h = (unsigned short)r;
    float hf = __uint_as_float(r << 16);
    float lo = x - hf;                       // exact in fp32
    unsigned u2 = __float_as_uint(lo);
    l = (unsigned short)((u2 + 0x7FFFu + ((u2 >> 16) & 1u)) >> 16);
}

// ---------------------------------------------------------------------------
// Kernel 0: transpose + bf16-split W matrices.  W[k][a] -> WT_hi/lo[a][k].
// ---------------------------------------------------------------------------
__global__ __launch_bounds__(256)
void prep_w(const float* __restrict__ Wh, const float* __restrict__ Wsm,
            unsigned short* __restrict__ WhTh, unsigned short* __restrict__ WhTl,
            unsigned short* __restrict__ WsTh, unsigned short* __restrict__ WsTl)
{
    __shared__ float lds[32][36];
    const int tid = threadIdx.x, bid = blockIdx.x;
    const int mat = bid >> 7, rem = bid & 127;
    const int k0 = (rem & 15) * 32, a0 = (rem >> 4) * 32;
    const float* W = mat ? Wsm : Wh;
    unsigned short* Oh = mat ? WsTh : WhTh;
    unsigned short* Ol = mat ? WsTl : WhTl;

    {
        int kl = tid >> 3, a4 = (tid & 7) * 4;
        float4 v = *(const float4*)&W[(size_t)(k0 + kl) * A_ + a0 + a4];
        lds[kl][a4] = v.x; lds[kl][a4 + 1] = v.y; lds[kl][a4 + 2] = v.z; lds[kl][a4 + 3] = v.w;
    }
    __syncthreads();
    {
        int al = tid >> 3, k4 = (tid & 7) * 4;
        unsigned short h[4], l[4];
        #pragma unroll
        for (int i = 0; i < 4; ++i) split_bf16(lds[k4 + i][al], h[i], l[i]);
        size_t o = (size_t)(a0 + al) * H_ + k0 + k4;
        *(ushort4*)&Oh[o] = make_ushort4(h[0], h[1], h[2], h[3]);
        *(ushort4*)&Ol[o] = make_ushort4(l[0], l[1], l[2], l[3]);
    }
}

// ---------------------------------------------------------------------------
// Kernel 1: split-bf16 MFMA GEMM + exp epilogue (unchanged, known-good).
//   blocks [0,256):   E[b][a][s] = exp(2*(enc@Wh + bh))  (transposed store)
//   blocks [256,320): D[m][a]    = exp(2*(dec@Ws + bs))  (row-major store)
// ---------------------------------------------------------------------------
__global__ __launch_bounds__(256)
void gemm_mfma(const float* __restrict__ enc, const float* __restrict__ dec,
               const unsigned short* __restrict__ WhTh, const unsigned short* __restrict__ WhTl,
               const unsigned short* __restrict__ WsTh, const unsigned short* __restrict__ WsTl,
               const float* __restrict__ bh, const float* __restrict__ bs,
               float* __restrict__ Ebuf, float* __restrict__ Dbuf)
{
    __shared__ short smem[8192];          // 16 KB: Ahi|Alo|Bhi|Blo, 4KB each
    short* Ah = smem;
    short* Al = smem + 2048;
    short* Bh = smem + 4096;
    short* Bl = smem + 6144;

    const int tid = threadIdx.x, bid = blockIdx.x;
    const bool isE = bid < 256;
    int mb, nb;
    const float* Ag; const unsigned short* WTh; const unsigned short* WTl; const float* bias;
    if (isE) { mb = (bid & 63) * 64; nb = (bid >> 6) * 64; Ag = enc; WTh = WhTh; WTl = WhTl; bias = bh; }
    else { int b2 = bid - 256; mb = (b2 & 15) * 64; nb = (b2 >> 4) * 64; Ag = dec; WTh = WsTh; WTl = WsTl; bias = bs; }

    const int m_l = tid >> 2, q = tid & 3;
    const size_t arow = (size_t)(mb + m_l) * H_ + 8 * q;   // A: fp32 [m][k]
    const size_t brow = (size_t)(nb + m_l) * H_ + 8 * q;   // WT: bf16 [a][k]
    const int woff = ((m_l >> 4) * 64 + (m_l & 15) + 16 * q) * 8;  // frag-major slot

    const int wave = tid >> 6, lane = tid & 63;
    const int wm = wave >> 1, wn = wave & 1;
    const int roffA = (2 * wm) * 512 + lane * 8;
    const int roffB = (2 * wn) * 512 + lane * 8;

    const int cl = lane & 15, rg = lane >> 4;
    const float bias0 = bias[nb + wn * 32 + cl];
    const float bias1 = bias[nb + wn * 32 + 16 + cl];

    f32x4 acc[2][2] = {};

    float4 aA = *(const float4*)&Ag[arow];
    float4 aB = *(const float4*)&Ag[arow + 4];
    short8 bHv = *(const short8*)&WTh[brow];
    short8 bLv = *(const short8*)&WTl[brow];

    for (int it = 0; it < 16; ++it) {
        __syncthreads();
        {
            float xs[8] = {aA.x, aA.y, aA.z, aA.w, aB.x, aB.y, aB.z, aB.w};
            short8 hv, lv;
            #pragma unroll
            for (int j = 0; j < 8; ++j) {
                unsigned short h, l; split_bf16(xs[j], h, l);
                hv[j] = (short)h; lv[j] = (short)l;
            }
            *(short8*)&Ah[woff] = hv;
            *(short8*)&Al[woff] = lv;
            *(short8*)&Bh[woff] = bHv;
            *(short8*)&Bl[woff] = bLv;
        }
        if (it < 15) {
            int kn = (it + 1) * 32;
            aA  = *(const float4*)&Ag[arow + kn];
            aB  = *(const float4*)&Ag[arow + kn + 4];
            bHv = *(const short8*)&WTh[brow + kn];
            bLv = *(const short8*)&WTl[brow + kn];
        }
        __syncthreads();
        short8 fAh0 = *(short8*)&Ah[roffA], fAh1 = *(short8*)&Ah[roffA + 512];
        short8 fAl0 = *(short8*)&Al[roffA], fAl1 = *(short8*)&Al[roffA + 512];
        short8 fBh0 = *(short8*)&Bh[roffB], fBh1 = *(short8*)&Bh[roffB + 512];
        short8 fBl0 = *(short8*)&Bl[roffB], fBl1 = *(short8*)&Bl[roffB + 512];
        acc[0][0] = __builtin_amdgcn_mfma_f32_16x16x32_bf16(fAh0, fBh0, acc[0][0], 0, 0, 0);
        acc[0][0] = __builtin_amdgcn_mfma_f32_16x16x32_bf16(fAh0, fBl0, acc[0][0], 0, 0, 0);
        acc[0][0] = __builtin_amdgcn_mfma_f32_16x16x32_bf16(fAl0, fBh0, acc[0][0], 0, 0, 0);
        acc[0][1] = __builtin_amdgcn_mfma_f32_16x16x32_bf16(fAh0, fBh1, acc[0][1], 0, 0, 0);
        acc[0][1] = __builtin_amdgcn_mfma_f32_16x16x32_bf16(fAh0, fBl1, acc[0][1], 0, 0, 0);
        acc[0][1] = __builtin_amdgcn_mfma_f32_16x16x32_bf16(fAl0, fBh1, acc[0][1], 0, 0, 0);
        acc[1][0] = __builtin_amdgcn_mfma_f32_16x16x32_bf16(fAh1, fBh0, acc[1][0], 0, 0, 0);
        acc[1][0] = __builtin_amdgcn_mfma_f32_16x16x32_bf16(fAh1, fBl0, acc[1][0], 0, 0, 0);
        acc[1][0] = __builtin_amdgcn_mfma_f32_16x16x32_bf16(fAl1, fBh0, acc[1][0], 0, 0, 0);
        acc[1][1] = __builtin_amdgcn_mfma_f32_16x16x32_bf16(fAh1, fBh1, acc[1][1], 0, 0, 0);
        acc[1][1] = __builtin_amdgcn_mfma_f32_16x16x32_bf16(fAh1, fBl1, acc[1][1], 0, 0, 0);
        acc[1][1] = __builtin_amdgcn_mfma_f32_16x16x32_bf16(fAl1, fBh1, acc[1][1], 0, 0, 0);
    }

    #pragma unroll
    for (int mf = 0; mf < 2; ++mf) {
        const int mg = mb + wm * 32 + mf * 16 + rg * 4;
        #pragma unroll
        for (int nf = 0; nf < 2; ++nf) {
            const int a = nb + wn * 32 + nf * 16 + cl;
            const float bb = nf ? bias1 : bias0;
            f32x4 ac = acc[mf][nf];
            float4 st;
            st.x = ex2((ac[0] + bb) * K2F);
            st.y = ex2((ac[1] + bb) * K2F);
            st.z = ex2((ac[2] + bb) * K2F);
            st.w = ex2((ac[3] + bb) * K2F);
            if (isE) {
                const int b = mg >> 10, s = mg & 1023;
                *(float4*)&Ebuf[(((size_t)b * A_ + a) << 10) + s] = st;
            } else {
                Dbuf[(size_t)(mg + 0) * A_ + a] = st.x;
                Dbuf[(size_t)(mg + 1) * A_ + a] = st.y;
                Dbuf[(size_t)(mg + 2) * A_ + a] = st.z;
                Dbuf[(size_t)(mg + 3) * A_ + a] = st.w;
            }
        }
    }
}

// ---------------------------------------------------------------------------
// Kernel 2: partial score sums, a-split for occupancy.
// block = (b, 2 t-rows, a-half h); grid 1024 = 4 blocks/CU candidate.
// Computes P[t][s] = sum_{a in half} Wv[a] / (E[b,a,s]*D[b,t,a] + 1).
// Math is f32x2-packed over the thread's two s-columns (v_pk_fma_f32 /
// v_pk_mul_f32, full-rate dual fp32) and 4 a-terms share ONE reciprocal:
//   sum w_i/q_i = [(w0q1+w1q0)q2q3 + (w2q3+w3q2)q0q1] / (q0q1q2q3)
// Range audit: q <= ~1.1e9 -> q^4 <= 1.5e36 < fp32 max. No softmax here;
// the merge kernel applies exp/normalize (shift-invariance makes the
// dropped constants and the skipped max-subtraction exact).
// ---------------------------------------------------------------------------
__device__ __forceinline__ void four_acc(const f32x2* ev, f32x2 d01, f32x2 d23,
                                         f32x2 w01, f32x2 w23, f32x2& acc)
{
    const f32x2 one = {1.0f, 1.0f};
    f32x2 q0 = __builtin_elementwise_fma(ev[0], splat2(d01.x), one);
    f32x2 q1 = __builtin_elementwise_fma(ev[1], splat2(d01.y), one);
    f32x2 q2 = __builtin_elementwise_fma(ev[2], splat2(d23.x), one);
    f32x2 q3 = __builtin_elementwise_fma(ev[3], splat2(d23.y), one);
    f32x2 q01 = q0 * q1, q23 = q2 * q3;
    f32x2 t01 = __builtin_elementwise_fma(splat2(w01.x), q1, splat2(w01.y) * q0);
    f32x2 t23 = __builtin_elementwise_fma(splat2(w23.x), q3, splat2(w23.y) * q2);
    f32x2 num = __builtin_elementwise_fma(t01, q23, t23 * q01);
    f32x2 den = q01 * q23;
    f32x2 r; r.x = rcpf_(den.x); r.y = rcpf_(den.y);
    acc = __builtin_elementwise_fma(num, r, acc);
}

#define LOADG(EV, DT, WW, G)                                            \
    { int ab_ = 4 * (G);                                                \
      EV[0] = *(const f32x2*)&Eb[(size_t)(ab_ + 0) << 10];              \
      EV[1] = *(const f32x2*)&Eb[(size_t)(ab_ + 1) << 10];              \
      EV[2] = *(const f32x2*)&Eb[(size_t)(ab_ + 2) << 10];              \
      EV[3] = *(const f32x2*)&Eb[(size_t)(ab_ + 3) << 10];              \
      DT[0] = *(const f32x2*)&Dsh[0][ab_];                              \
      DT[1] = *(const f32x2*)&Dsh[0][ab_ + 2];                          \
      DT[2] = *(const f32x2*)&Dsh[1][ab_];                              \
      DT[3] = *(const f32x2*)&Dsh[1][ab_ + 2];                          \
      WW[0] = *(const f32x2*)&Wsh[ab_];                                 \
      WW[1] = *(const f32x2*)&Wsh[ab_ + 2]; }

__global__ __launch_bounds__(512, 6)
void score_partial(const float* __restrict__ E, const float* __restrict__ D,
                   const float* __restrict__ Wv,
                   float* __restrict__ P0, float* __restrict__ P1)
{
    const int tid = threadIdx.x;
    const int bid = blockIdx.x;
    const int b   = bid >> 8;
    const int rem = bid & 255;
    const int h   = rem & 1;                  // a-half
    const int t0  = (rem >> 1) * 2;
    const int abase = h * 128;

    __shared__ float Dsh[2][128];
    __shared__ float Wsh[128];

    if (tid < 64) {
        int r = tid >> 5, c4 = (tid & 31) << 2;
        *(float4*)&Dsh[r][c4] = *(const float4*)&D[((size_t)b * T_ + t0 + r) * A_ + abase + c4];
    } else if (tid < 96) {
        int c4 = (tid - 64) << 2;
        *(float4*)&Wsh[c4] = *(const float4*)&Wv[abase + c4];
    }
    __syncthreads();

    const int s0 = tid << 1;                  // two adjacent s columns
    const float* Eb = E + ((size_t)b * A_ + abase) * S_ + s0;

    f32x2 acc0 = {0.0f, 0.0f}, acc1 = {0.0f, 0.0f};
    f32x2 evA[4], evB[4], dA[4], dB[4], wA[2], wB[2];

    LOADG(evA, dA, wA, 0);
    for (int g = 0; g < 32; g += 2) {
        LOADG(evB, dB, wB, g + 1);
        four_acc(evA, dA[0], dA[1], wA[0], wA[1], acc0);
        four_acc(evA, dA[2], dA[3], wA[0], wA[1], acc1);
        if (g + 2 < 32) LOADG(evA, dA, wA, g + 2);
        four_acc(evB, dB[0], dB[1], wB[0], wB[1], acc0);
        four_acc(evB, dB[2], dB[3], wB[0], wB[1], acc1);
    }

    float* Pd = h ? P1 : P0;
    *(f32x2*)&Pd[((size_t)b * T_ + t0)     * S_ + s0] = acc0;
    *(f32x2*)&Pd[((size_t)b * T_ + t0 + 1) * S_ + s0] = acc1;
}
#undef LOADG

// ---------------------------------------------------------------------------
// Kernel 3: merge halves + softmax. block = one (b,t) row; 256 thr x 4 s.
// score' = -2*(P0+P1); softmax without max-subtraction (|score'| <= ~26,
// exp2 args safe; normalization cancels any shift exactly).
// P0 lives in d_out; in-place read->write is safe (each thread owns its s).
// ---------------------------------------------------------------------------
__global__ __launch_bounds__(256)
void merge_softmax(const float* __restrict__ P1, float* __restrict__ outp)
{
    const int row = blockIdx.x;               // b*T + t
    const int tid = threadIdx.x;
    const int lane = tid & 63, wid = tid >> 6;
    __shared__ float red[4];

    float* o = outp + (size_t)row * S_;
    const float* p1 = P1 + (size_t)row * S_;
    const int s4 = tid << 2;

    float4 a = *(const float4*)&o[s4];
    float4 c = *(const float4*)&p1[s4];
    float e0 = ex2((a.x + c.x) * -K2F);
    float e1 = ex2((a.y + c.y) * -K2F);
    float e2 = ex2((a.z + c.z) * -K2F);
    float e3 = ex2((a.w + c.w) * -K2F);

    float ssum = (e0 + e1) + (e2 + e3);
    #pragma unroll
    for (int off = 32; off > 0; off >>= 1) ssum += __shfl_xor(ssum, off, 64);
    if (lane == 0) red[wid] = ssum;
    __syncthreads();
    float tot = (red[0] + red[1]) + (red[2] + red[3]);
    float inv = 1.0f / tot;

    *(float4*)&o[s4] = make_float4(e0 * inv, e1 * inv, e2 * inv, e3 * inv);
}

// ---------------------------------------------------------------------------
extern "C" void kernel_launch(void* const* d_in, const int* in_sizes, int n_in,
                              void* d_out, int out_size, void* d_ws, size_t ws_size,
                              hipStream_t stream)
{
    const float* enc = (const float*)d_in[0];
    const float* dec = (const float*)d_in[1];
    const float* Wh  = (const float*)d_in[2];
    const float* bh  = (const float*)d_in[3];
    const float* Wsm = (const float*)d_in[4];
    const float* bs  = (const float*)d_in[5];
    const float* Wv  = (const float*)d_in[6];
    // d_in[7] (bv) intentionally unused: softmax is shift-invariant.

    float* Ebuf = (float*)d_ws;                              // 1M floats (4 MB)
    float* Dbuf = Ebuf + (size_t)B_ * A_ * S_;               // 256K floats (1 MB)
    unsigned short* wt = (unsigned short*)(Dbuf + (size_t)B_ * T_ * A_);
    unsigned short* WhTh = wt;                               // 256x512 bf16 each
    unsigned short* WhTl = wt + 131072;
    unsigned short* WsTh = wt + 262144;
    unsigned short* WsTl = wt + 393216;
    float* P1 = (float*)(wt + 524288);                       // 1M floats (4 MB)
    float* P0 = (float*)d_out;                               // partial 0 in-place

    prep_w<<<256, 256, 0, stream>>>(Wh, Wsm, WhTh, WhTl, WsTh, WsTl);
    gemm_mfma<<<320, 256, 0, stream>>>(enc, dec, WhTh, WhTl, WsTh, WsTl,
                                       bh, bs, Ebuf, Dbuf);
    score_partial<<<B_ * 256, 512, 0, stream>>>(Ebuf, Dbuf, Wv, P0, P1);
    merge_softmax<<<B_ * T_, 256, 0, stream>>>(P1, (float*)d_out);
}

// Round 7
// 56.090 us; speedup vs baseline: 2.6657x; 1.1690x over previous
//
#include <hip/hip_runtime.h>

// Problem dims (fixed by setup_inputs): B=4, S=1024, T=256, H=512, A=256
#define B_ 4
#define S_ 1024
#define T_ 256
#define H_ 512
#define A_ 256

typedef __attribute__((ext_vector_type(8))) short short8;   // 8 bf16 = 4 VGPR
typedef __attribute__((ext_vector_type(4))) float f32x4;    // MFMA acc

__device__ __forceinline__ float ex2(float x)   { return __builtin_amdgcn_exp2f(x); }
__device__ __forceinline__ float rcpf_(float x) { return __builtin_amdgcn_rcpf(x); }

#define K2F 2.8853900817779268f     // 2*log2(e): exp(2x) = exp2(K2F*x)

// fp32 -> bf16 split: x ~= hi + lo (both bf16, RNE).
__device__ __forceinline__ void split_bf16(float x, unsigned short& h, unsigned short& l)
{
    unsigned u = __float_as_uint(x);
    unsigned r = (u + 0x7FFFu + ((u >> 16) & 1u)) >> 16;
    h = (unsigned short)r;
    float hf = __uint_as_float(r << 16);
    float lo = x - hf;                       // exact in fp32
    unsigned u2 = __float_as_uint(lo);
    l = (unsigned short)((u2 + 0x7FFFu + ((u2 >> 16) & 1u)) >> 16);
}

// ---------------------------------------------------------------------------
// Kernel 0: transpose + bf16-split W matrices.  W[k][a] -> WT_hi/lo[a][k].
// ---------------------------------------------------------------------------
__global__ __launch_bounds__(256)
void prep_w(const float* __restrict__ Wh, const float* __restrict__ Wsm,
            unsigned short* __restrict__ WhTh, unsigned short* __restrict__ WhTl,
            unsigned short* __restrict__ WsTh, unsigned short* __restrict__ WsTl)
{
    __shared__ float lds[32][36];
    const int tid = threadIdx.x, bid = blockIdx.x;
    const int mat = bid >> 7, rem = bid & 127;
    const int k0 = (rem & 15) * 32, a0 = (rem >> 4) * 32;
    const float* W = mat ? Wsm : Wh;
    unsigned short* Oh = mat ? WsTh : WhTh;
    unsigned short* Ol = mat ? WsTl : WhTl;

    {
        int kl = tid >> 3, a4 = (tid & 7) * 4;
        float4 v = *(const float4*)&W[(size_t)(k0 + kl) * A_ + a0 + a4];
        lds[kl][a4] = v.x; lds[kl][a4 + 1] = v.y; lds[kl][a4 + 2] = v.z; lds[kl][a4 + 3] = v.w;
    }
    __syncthreads();
    {
        int al = tid >> 3, k4 = (tid & 7) * 4;
        unsigned short h[4], l[4];
        #pragma unroll
        for (int i = 0; i < 4; ++i) split_bf16(lds[k4 + i][al], h[i], l[i]);
        size_t o = (size_t)(a0 + al) * H_ + k0 + k4;
        *(ushort4*)&Oh[o] = make_ushort4(h[0], h[1], h[2], h[3]);
        *(ushort4*)&Ol[o] = make_ushort4(l[0], l[1], l[2], l[3]);
    }
}

// ---------------------------------------------------------------------------
// Kernel 1: split-bf16 MFMA GEMM + exp epilogue (unchanged, known-good).
//   blocks [0,256):   E[b][a][s] = exp(2*(enc@Wh + bh))  (transposed store)
//   blocks [256,320): D[m][a]    = exp(2*(dec@Ws + bs))  (row-major store)
// ---------------------------------------------------------------------------
__global__ __launch_bounds__(256)
void gemm_mfma(const float* __restrict__ enc, const float* __restrict__ dec,
               const unsigned short* __restrict__ WhTh, const unsigned short* __restrict__ WhTl,
               const unsigned short* __restrict__ WsTh, const unsigned short* __restrict__ WsTl,
               const float* __restrict__ bh, const float* __restrict__ bs,
               float* __restrict__ Ebuf, float* __restrict__ Dbuf)
{
    __shared__ short smem[8192];          // 16 KB: Ahi|Alo|Bhi|Blo, 4KB each
    short* Ah = smem;
    short* Al = smem + 2048;
    short* Bh = smem + 4096;
    short* Bl = smem + 6144;

    const int tid = threadIdx.x, bid = blockIdx.x;
    const bool isE = bid < 256;
    int mb, nb;
    const float* Ag; const unsigned short* WTh; const unsigned short* WTl; const float* bias;
    if (isE) { mb = (bid & 63) * 64; nb = (bid >> 6) * 64; Ag = enc; WTh = WhTh; WTl = WhTl; bias = bh; }
    else { int b2 = bid - 256; mb = (b2 & 15) * 64; nb = (b2 >> 4) * 64; Ag = dec; WTh = WsTh; WTl = WsTl; bias = bs; }

    const int m_l = tid >> 2, q = tid & 3;
    const size_t arow = (size_t)(mb + m_l) * H_ + 8 * q;   // A: fp32 [m][k]
    const size_t brow = (size_t)(nb + m_l) * H_ + 8 * q;   // WT: bf16 [a][k]
    const int woff = ((m_l >> 4) * 64 + (m_l & 15) + 16 * q) * 8;  // frag-major slot

    const int wave = tid >> 6, lane = tid & 63;
    const int wm = wave >> 1, wn = wave & 1;
    const int roffA = (2 * wm) * 512 + lane * 8;
    const int roffB = (2 * wn) * 512 + lane * 8;

    const int cl = lane & 15, rg = lane >> 4;
    const float bias0 = bias[nb + wn * 32 + cl];
    const float bias1 = bias[nb + wn * 32 + 16 + cl];

    f32x4 acc[2][2] = {};

    float4 aA = *(const float4*)&Ag[arow];
    float4 aB = *(const float4*)&Ag[arow + 4];
    short8 bHv = *(const short8*)&WTh[brow];
    short8 bLv = *(const short8*)&WTl[brow];

    for (int it = 0; it < 16; ++it) {
        __syncthreads();
        {
            float xs[8] = {aA.x, aA.y, aA.z, aA.w, aB.x, aB.y, aB.z, aB.w};
            short8 hv, lv;
            #pragma unroll
            for (int j = 0; j < 8; ++j) {
                unsigned short h, l; split_bf16(xs[j], h, l);
                hv[j] = (short)h; lv[j] = (short)l;
            }
            *(short8*)&Ah[woff] = hv;
            *(short8*)&Al[woff] = lv;
            *(short8*)&Bh[woff] = bHv;
            *(short8*)&Bl[woff] = bLv;
        }
        if (it < 15) {
            int kn = (it + 1) * 32;
            aA  = *(const float4*)&Ag[arow + kn];
            aB  = *(const float4*)&Ag[arow + kn + 4];
            bHv = *(const short8*)&WTh[brow + kn];
            bLv = *(const short8*)&WTl[brow + kn];
        }
        __syncthreads();
        short8 fAh0 = *(short8*)&Ah[roffA], fAh1 = *(short8*)&Ah[roffA + 512];
        short8 fAl0 = *(short8*)&Al[roffA], fAl1 = *(short8*)&Al[roffA + 512];
        short8 fBh0 = *(short8*)&Bh[roffB], fBh1 = *(short8*)&Bh[roffB + 512];
        short8 fBl0 = *(short8*)&Bl[roffB], fBl1 = *(short8*)&Bl[roffB + 512];
        acc[0][0] = __builtin_amdgcn_mfma_f32_16x16x32_bf16(fAh0, fBh0, acc[0][0], 0, 0, 0);
        acc[0][0] = __builtin_amdgcn_mfma_f32_16x16x32_bf16(fAh0, fBl0, acc[0][0], 0, 0, 0);
        acc[0][0] = __builtin_amdgcn_mfma_f32_16x16x32_bf16(fAl0, fBh0, acc[0][0], 0, 0, 0);
        acc[0][1] = __builtin_amdgcn_mfma_f32_16x16x32_bf16(fAh0, fBh1, acc[0][1], 0, 0, 0);
        acc[0][1] = __builtin_amdgcn_mfma_f32_16x16x32_bf16(fAh0, fBl1, acc[0][1], 0, 0, 0);
        acc[0][1] = __builtin_amdgcn_mfma_f32_16x16x32_bf16(fAl0, fBh1, acc[0][1], 0, 0, 0);
        acc[1][0] = __builtin_amdgcn_mfma_f32_16x16x32_bf16(fAh1, fBh0, acc[1][0], 0, 0, 0);
        acc[1][0] = __builtin_amdgcn_mfma_f32_16x16x32_bf16(fAh1, fBl0, acc[1][0], 0, 0, 0);
        acc[1][0] = __builtin_amdgcn_mfma_f32_16x16x32_bf16(fAl1, fBh0, acc[1][0], 0, 0, 0);
        acc[1][1] = __builtin_amdgcn_mfma_f32_16x16x32_bf16(fAh1, fBh1, acc[1][1], 0, 0, 0);
        acc[1][1] = __builtin_amdgcn_mfma_f32_16x16x32_bf16(fAh1, fBl1, acc[1][1], 0, 0, 0);
        acc[1][1] = __builtin_amdgcn_mfma_f32_16x16x32_bf16(fAl1, fBh1, acc[1][1], 0, 0, 0);
    }

    #pragma unroll
    for (int mf = 0; mf < 2; ++mf) {
        const int mg = mb + wm * 32 + mf * 16 + rg * 4;
        #pragma unroll
        for (int nf = 0; nf < 2; ++nf) {
            const int a = nb + wn * 32 + nf * 16 + cl;
            const float bb = nf ? bias1 : bias0;
            f32x4 ac = acc[mf][nf];
            float4 st;
            st.x = ex2((ac[0] + bb) * K2F);
            st.y = ex2((ac[1] + bb) * K2F);
            st.z = ex2((ac[2] + bb) * K2F);
            st.w = ex2((ac[3] + bb) * K2F);
            if (isE) {
                const int b = mg >> 10, s = mg & 1023;
                *(float4*)&Ebuf[(((size_t)b * A_ + a) << 10) + s] = st;
            } else {
                Dbuf[(size_t)(mg + 0) * A_ + a] = st.x;
                Dbuf[(size_t)(mg + 1) * A_ + a] = st.y;
                Dbuf[(size_t)(mg + 2) * A_ + a] = st.z;
                Dbuf[(size_t)(mg + 3) * A_ + a] = st.w;
            }
        }
    }
}

// ---------------------------------------------------------------------------
// Kernel 2: partial score sums. TT=4 t-rows, AS-way a-split.
// block = (b, 4 t-rows, a-chunk h); 512 threads x 2 adjacent s columns.
// P[t][s] = sum_{a in chunk} Wv[a] / (E[b,a,s]*D[b,t,a] + 1).
// Pure-scalar math, 4 a-terms share one reciprocal (14 VALU + 1 rcp per
// 4 elements = 3.5 VALU/elem); D/W read as single uniform (broadcast)
// b128 LDS reads; E double-buffered in registers. No exp here; merge
// kernel applies exp2/normalize (softmax shift-invariance = exact).
// ---------------------------------------------------------------------------
template<int AS>
__global__ __launch_bounds__(512)
void score_partial(const float* __restrict__ E, const float* __restrict__ D,
                   const float* __restrict__ Wv,
                   float* __restrict__ P0, float* __restrict__ P1,
                   float* __restrict__ P2, float* __restrict__ P3)
{
    constexpr int ABLK = 256 / AS;       // a per block
    constexpr int NG   = ABLK / 4;       // 4-a groups

    const int tid = threadIdx.x;
    const int bid = blockIdx.x;
    const int b   = bid / (64 * AS);
    const int rem = bid % (64 * AS);
    const int h   = rem & (AS - 1);
    const int t0  = (rem / AS) * 4;
    const int abase = h * ABLK;

    __shared__ float Dsh[4][ABLK];
    __shared__ float Wsh[ABLK];

    if (tid < ABLK) {
        int r = tid / (ABLK / 4), c4 = (tid % (ABLK / 4)) << 2;
        *(float4*)&Dsh[r][c4] = *(const float4*)&D[((size_t)b * T_ + t0 + r) * A_ + abase + c4];
    } else if (tid < ABLK + ABLK / 4) {
        int c4 = (tid - ABLK) << 2;
        *(float4*)&Wsh[c4] = *(const float4*)&Wv[abase + c4];
    }
    __syncthreads();

    const int s0 = tid << 1;
    const float* Eb = E + ((size_t)b * A_ + abase) * S_ + s0;

    float accx[4] = {}, accy[4] = {};
    float2 evA[4], evB[4];

    #pragma unroll
    for (int j = 0; j < 4; ++j) evA[j] = *(const float2*)&Eb[(size_t)j * S_];

    auto compute = [&](const float2* ev, int g) {
        float4 w = *(const float4*)&Wsh[g * 4];
        #pragma unroll
        for (int t = 0; t < 4; ++t) {
            float4 d = *(const float4*)&Dsh[t][g * 4];
            {   // s column 0
                float q0 = fmaf(ev[0].x, d.x, 1.0f);
                float q1 = fmaf(ev[1].x, d.y, 1.0f);
                float q2 = fmaf(ev[2].x, d.z, 1.0f);
                float q3 = fmaf(ev[3].x, d.w, 1.0f);
                float q01 = q0 * q1, q23 = q2 * q3;
                float n1 = fmaf(w.x, q1, w.y * q0);
                float n2 = fmaf(w.z, q3, w.w * q2);
                float num = fmaf(n1, q23, n2 * q01);
                accx[t] = fmaf(num, rcpf_(q01 * q23), accx[t]);
            }
            {   // s column 1
                float q0 = fmaf(ev[0].y, d.x, 1.0f);
                float q1 = fmaf(ev[1].y, d.y, 1.0f);
                float q2 = fmaf(ev[2].y, d.z, 1.0f);
                float q3 = fmaf(ev[3].y, d.w, 1.0f);
                float q01 = q0 * q1, q23 = q2 * q3;
                float n1 = fmaf(w.x, q1, w.y * q0);
                float n2 = fmaf(w.z, q3, w.w * q2);
                float num = fmaf(n1, q23, n2 * q01);
                accy[t] = fmaf(num, rcpf_(q01 * q23), accy[t]);
            }
        }
    };

    for (int g = 0; g < NG; g += 2) {
        #pragma unroll
        for (int j = 0; j < 4; ++j) evB[j] = *(const float2*)&Eb[(size_t)((g + 1) * 4 + j) * S_];
        compute(evA, g);
        if (g + 2 < NG) {
            #pragma unroll
            for (int j = 0; j < 4; ++j) evA[j] = *(const float2*)&Eb[(size_t)((g + 2) * 4 + j) * S_];
        }
        compute(evB, g + 1);
    }

    float* Pd = (h == 0) ? P0 : (h == 1) ? P1 : (h == 2) ? P2 : P3;
    #pragma unroll
    for (int t = 0; t < 4; ++t) {
        float2 o; o.x = accx[t]; o.y = accy[t];
        *(float2*)&Pd[((size_t)b * T_ + t0 + t) * S_ + s0] = o;
    }
}

// ---------------------------------------------------------------------------
// Kernel 3: merge NP partials + softmax. block = one (b,t) row; 256 thr x 4 s.
// score' = -2*sum(P); softmax without max-subtraction (|score'| <= ~26, exp2
// args safe in fp32; normalization cancels the shift exactly).
// P0 lives in d_out; in-place read->write safe (each thread owns its s).
// ---------------------------------------------------------------------------
template<int NP>
__global__ __launch_bounds__(256)
void merge_softmax(const float* __restrict__ P1, const float* __restrict__ P2,
                   const float* __restrict__ P3, float* __restrict__ outp)
{
    const int row = blockIdx.x;               // b*T + t
    const int tid = threadIdx.x;
    const int lane = tid & 63, wid = tid >> 6;
    __shared__ float red[4];

    float* o = outp + (size_t)row * S_;
    const int s4 = tid << 2;

    float4 a = *(const float4*)&o[s4];
    {
        float4 c = *(const float4*)&P1[(size_t)row * S_ + s4];
        a.x += c.x; a.y += c.y; a.z += c.z; a.w += c.w;
    }
    if (NP >= 4) {
        float4 c = *(const float4*)&P2[(size_t)row * S_ + s4];
        a.x += c.x; a.y += c.y; a.z += c.z; a.w += c.w;
        float4 e = *(const float4*)&P3[(size_t)row * S_ + s4];
        a.x += e.x; a.y += e.y; a.z += e.z; a.w += e.w;
    }
    float e0 = ex2(a.x * -K2F);
    float e1 = ex2(a.y * -K2F);
    float e2 = ex2(a.z * -K2F);
    float e3 = ex2(a.w * -K2F);

    float ssum = (e0 + e1) + (e2 + e3);
    #pragma unroll
    for (int off = 32; off > 0; off >>= 1) ssum += __shfl_xor(ssum, off, 64);
    if (lane == 0) red[wid] = ssum;
    __syncthreads();
    float tot = (red[0] + red[1]) + (red[2] + red[3]);
    float inv = 1.0f / tot;

    *(float4*)&o[s4] = make_float4(e0 * inv, e1 * inv, e2 * inv, e3 * inv);
}

// ---------------------------------------------------------------------------
extern "C" void kernel_launch(void* const* d_in, const int* in_sizes, int n_in,
                              void* d_out, int out_size, void* d_ws, size_t ws_size,
                              hipStream_t stream)
{
    const float* enc = (const float*)d_in[0];
    const float* dec = (const float*)d_in[1];
    const float* Wh  = (const float*)d_in[2];
    const float* bh  = (const float*)d_in[3];
    const float* Wsm = (const float*)d_in[4];
    const float* bs  = (const float*)d_in[5];
    const float* Wv  = (const float*)d_in[6];
    // d_in[7] (bv) intentionally unused: softmax is shift-invariant.

    char* ws = (char*)d_ws;
    float* Ebuf = (float*)ws;                                // [0,4MB)
    float* Dbuf = (float*)(ws + (4 << 20));                  // [4,5MB)
    unsigned short* wt = (unsigned short*)(ws + (5 << 20));  // [5,6MB)
    unsigned short* WhTh = wt;
    unsigned short* WhTl = wt + 131072;
    unsigned short* WsTh = wt + 262144;
    unsigned short* WsTl = wt + 393216;
    float* P1 = (float*)(ws + (6 << 20));                    // [6,10MB)
    float* P2 = (float*)(ws + (10 << 20));                   // [10,14MB)
    float* P3 = (float*)(ws + (14 << 20));                   // [14,18MB)
    float* P0 = (float*)d_out;                               // partial 0 in-place

    prep_w<<<256, 256, 0, stream>>>(Wh, Wsm, WhTh, WhTl, WsTh, WsTl);
    gemm_mfma<<<320, 256, 0, stream>>>(enc, dec, WhTh, WhTl, WsTh, WsTl,
                                       bh, bs, Ebuf, Dbuf);
    if (ws_size >= (size_t)(18 << 20)) {
        score_partial<4><<<B_ * 256, 512, 0, stream>>>(Ebuf, Dbuf, Wv, P0, P1, P2, P3);
        merge_softmax<4><<<B_ * T_, 256, 0, stream>>>(P1, P2, P3, (float*)d_out);
    } else {
        score_partial<2><<<B_ * 128, 512, 0, stream>>>(Ebuf, Dbuf, Wv, P0, P1, P2, P3);
        merge_softmax<2><<<B_ * T_, 256, 0, stream>>>(P1, P2, P3, (float*)d_out);
    }
}